// Round 3
// baseline (194.239 us; speedup 1.0000x reference)
//
#include <hip/hip_runtime.h>
#include <hip/hip_bf16.h>

// relu(x[n,k,:] @ W + b) max-pooled over k.
// x: [100000, 32, 64] f32, W: [64, 64] f32 ([n_in][n_out]), b: [64] f32
// out: [100000, 64] f32
//
// R0 structure (best known: 160.4 us) + nontemporal x loads / out stores.
// x (819 MB) is streamed exactly once -- 3.2x L3, 25x aggregate L2 -- so
// default cache allocation only pollutes. nt bit = no-allocate streaming.
// One wave per node, bf16 MFMA 16x16x32, W in registers, no LDS.
// HBM floor: 845 MB -> ~134 us at 6.3 TB/s copy ceiling.

typedef __attribute__((ext_vector_type(8))) short bf16x8;
typedef __attribute__((ext_vector_type(4))) float f32x4;

#define KNEIGH 32
#define NIN 64
#define NOUT 64

__device__ __forceinline__ short f2bf(float f) {
    __hip_bfloat16 h = __float2bfloat16(f);
    return __builtin_bit_cast(short, h);
}

__global__ __launch_bounds__(256) void edge_mfma_kernel(
    const float* __restrict__ x, const float* __restrict__ W,
    const float* __restrict__ b, float* __restrict__ out,
    int n_nodes, int wave_stride)
{
    const int lane = threadIdx.x & 63;
    const int l16  = lane & 15;   // col within 16-wide tile / row within A M-tile
    const int lg   = lane >> 4;   // lane group 0..3

    // ---- per-wave constants: W as 8 B-fragments (4 N-tiles x 2 K-steps), bias ----
    // B layout for 16x16x32: col n = lane&15, k = (lane>>4)*8 + j
    // W is 16 KB, L2-resident after first waves -> normal (cached) loads.
    bf16x8 Wf[4][2];
#pragma unroll
    for (int t = 0; t < 4; ++t) {
#pragma unroll
        for (int s = 0; s < 2; ++s) {
#pragma unroll
            for (int j = 0; j < 8; ++j) {
                int k = s * 32 + lg * 8 + j;   // n_in index
                int o = t * 16 + l16;          // n_out index
                Wf[t][s][j] = f2bf(W[k * NOUT + o]);
            }
        }
    }
    float bias[4];
#pragma unroll
    for (int t = 0; t < 4; ++t) bias[t] = b[t * 16 + l16];

    const int wave = blockIdx.x * (blockDim.x >> 6) + (threadIdx.x >> 6);

    for (int n = wave; n < n_nodes; n += wave_stride) {
        const float* xb = x + (size_t)n * (KNEIGH * NIN);

        // ---- load x fragments (nontemporal: streamed once, don't cache) ----
        // A layout: row m = lane&15, k = (lane>>4)*8 + j -> 2x dwordx4 per (m,s)
        f32x4 xr[2][2][2];
#pragma unroll
        for (int m = 0; m < 2; ++m) {
#pragma unroll
            for (int s = 0; s < 2; ++s) {
                const f32x4* p = reinterpret_cast<const f32x4*>(
                    xb + (m * 16 + l16) * NIN + s * 32 + lg * 8);
                xr[m][s][0] = __builtin_nontemporal_load(p);
                xr[m][s][1] = __builtin_nontemporal_load(p + 1);
            }
        }

        // ---- convert to bf16 A-fragments ----
        bf16x8 Af[2][2];
#pragma unroll
        for (int m = 0; m < 2; ++m) {
#pragma unroll
            for (int s = 0; s < 2; ++s) {
#pragma unroll
                for (int j = 0; j < 4; ++j) {
                    Af[m][s][j]     = f2bf(xr[m][s][0][j]);
                    Af[m][s][4 + j] = f2bf(xr[m][s][1][j]);
                }
            }
        }

        // ---- 16 MFMAs: acc[m][t] over 2 K-steps ----
        f32x4 acc[2][4];
#pragma unroll
        for (int m = 0; m < 2; ++m)
#pragma unroll
            for (int t = 0; t < 4; ++t)
                acc[m][t] = (f32x4){0.f, 0.f, 0.f, 0.f};

#pragma unroll
        for (int m = 0; m < 2; ++m) {
#pragma unroll
            for (int t = 0; t < 4; ++t) {
                acc[m][t] = __builtin_amdgcn_mfma_f32_16x16x32_bf16(
                    Af[m][0], Wf[t][0], acc[m][t], 0, 0, 0);
                acc[m][t] = __builtin_amdgcn_mfma_f32_16x16x32_bf16(
                    Af[m][1], Wf[t][1], acc[m][t], 0, 0, 0);
            }
        }

        // ---- epilogue: max over 32 rows per column, then relu(max + bias) ----
        // C/D layout: col = lane&15, row = (lane>>4)*4 + reg (+16 for m-tile 1)
        float res[4];
#pragma unroll
        for (int t = 0; t < 4; ++t) {
            float v0 = fmaxf(acc[0][t][0], acc[1][t][0]);
            float v1 = fmaxf(acc[0][t][1], acc[1][t][1]);
            float v2 = fmaxf(acc[0][t][2], acc[1][t][2]);
            float v3 = fmaxf(acc[0][t][3], acc[1][t][3]);
            float r = fmaxf(fmaxf(v0, v1), fmaxf(v2, v3));
            r = fmaxf(r, __shfl_xor(r, 16));
            r = fmaxf(r, __shfl_xor(r, 32));
            res[t] = fmaxf(r + bias[t], 0.0f);
        }

        float val = (lg == 0) ? res[0] : (lg == 1) ? res[1] : (lg == 2) ? res[2] : res[3];
        __builtin_nontemporal_store(val, &out[(size_t)n * NOUT + lane]);
    }
}

extern "C" void kernel_launch(void* const* d_in, const int* in_sizes, int n_in,
                              void* d_out, int out_size, void* d_ws, size_t ws_size,
                              hipStream_t stream) {
    const float* x = (const float*)d_in[0];
    const float* W = (const float*)d_in[1];
    const float* b = (const float*)d_in[2];
    float* out = (float*)d_out;

    const int n_nodes = in_sizes[0] / (KNEIGH * NIN);  // 100000
    const int blocks = 2048;                           // grid-stride, 4 waves/block
    const int wave_stride = blocks * 4;

    hipLaunchKernelGGL(edge_mfma_kernel, dim3(blocks), dim3(256), 0, stream,
                       x, W, b, out, n_nodes, wave_stride);
}

// Round 4
// 165.687 us; speedup vs baseline: 1.1723x; 1.1723x over previous
//
#include <hip/hip_runtime.h>
#include <hip/hip_bf16.h>

// relu(x[n,k,:] @ W + b) max-pooled over k.
// x: [100000, 32, 64] f32, W: [64, 64] f32 ([n_in][n_out]), b: [64] f32
// out: [100000, 64] f32
//
// One wave per node, bf16 MFMA 16x16x32, W in registers.
// x path: 8x global_load_lds (each a fully-contiguous 1KB wave footprint,
// XOR-swizzled source so ds_read_b128 fragment reads are bank-conflict-floor),
// single 8KB LDS buffer per wave, next node's loads issued right after this
// node's ds_reads complete -> HBM latency hidden under MFMA+epilogue with
// zero VGPR cost. HBM floor: 845 MB -> ~134 us at 6.3 TB/s.

typedef __attribute__((ext_vector_type(8))) short bf16x8;
typedef __attribute__((ext_vector_type(4))) float f32x4;

#define KNEIGH 32
#define NIN 64
#define NOUT 64
#define NODE_ELTS (KNEIGH * NIN)   // 2048 f32 = 8 KB

__device__ __forceinline__ short f2bf(float f) {
    __hip_bfloat16 h = __float2bfloat16(f);
    return __builtin_bit_cast(short, h);
}

// async global->LDS, 16B per lane; gsrc is PER-LANE, lds dest is wave-uniform
// base + lane*16 (linear). Size must be a literal.
__device__ __forceinline__ void gload16(const float* gsrc, float* lds_base) {
    __builtin_amdgcn_global_load_lds(
        (const __attribute__((address_space(1))) unsigned int*)gsrc,
        (__attribute__((address_space(3))) unsigned int*)lds_base, 16, 0, 0);
}

__global__ __launch_bounds__(256, 4) void edge_mfma_kernel(
    const float* __restrict__ x, const float* __restrict__ W,
    const float* __restrict__ b, float* __restrict__ out,
    int n_nodes, int wave_stride)
{
    __shared__ float lds[4][NODE_ELTS];   // 8 KB per wave, 32 KB per block

    const int lane = threadIdx.x & 63;
    const int l16  = lane & 15;
    const int lg   = lane >> 4;
    const int wid  = threadIdx.x >> 6;
    float* my = lds[wid];

    // ---- per-wave constants: W as 8 B-fragments, bias (same as R0) ----
    bf16x8 Wf[4][2];
#pragma unroll
    for (int t = 0; t < 4; ++t) {
#pragma unroll
        for (int s = 0; s < 2; ++s) {
#pragma unroll
            for (int j = 0; j < 8; ++j) {
                int k = s * 32 + lg * 8 + j;
                int o = t * 16 + l16;
                Wf[t][s][j] = f2bf(W[k * NOUT + o]);
            }
        }
    }
    float bias[4];
#pragma unroll
    for (int t = 0; t < 4; ++t) bias[t] = b[t * 16 + l16];

    // ---- per-lane swizzled global source offsets (loop-invariant) ----
    // gload instr i writes LDS 16B-unit (row r = i*4 + lg', col unit c = lane&15).
    // Store global unit (r, c ^ (r&15)) there  ->  source f32 offset:
    int goff[8];
#pragma unroll
    for (int i = 0; i < 8; ++i) {
        int r = i * 4 + lg;                 // this lane's dest row for instr i
        int cu = l16 ^ (r & 15);            // swizzled source 16B-unit in row
        goff[i] = r * 64 + cu * 4;          // f32 elements
    }

    const int S = wave_stride;
    int n = blockIdx.x * 4 + wid;
    if (n >= n_nodes) return;

    // ---- prologue: issue loads for first node ----
    {
        const float* xb = x + (size_t)n * NODE_ELTS;
#pragma unroll
        for (int i = 0; i < 8; ++i) gload16(xb + goff[i], my + i * 256);
    }

    for (; n < n_nodes; n += S) {
        const int nn = n + S;

        // wait: node n's 8KB is in LDS (single wave owns buffer, no barrier)
        asm volatile("s_waitcnt vmcnt(0)" ::: "memory");
        __builtin_amdgcn_sched_barrier(0);

        // ---- ds_read fragments (swizzled addresses, bank-conflict floor) ----
        // global f32 (r, s*32+lg*8+w*4+jj)  lives at LDS unit (s*8+lg*2+w)^ (r&15)
        f32x4 q[2][2][2];
#pragma unroll
        for (int m = 0; m < 2; ++m) {
#pragma unroll
            for (int s = 0; s < 2; ++s) {
#pragma unroll
                for (int w = 0; w < 2; ++w) {
                    int r = m * 16 + l16;
                    int u = (s * 8 + lg * 2 + w) ^ l16;   // r&15 == l16
                    q[m][s][w] = *reinterpret_cast<const f32x4*>(my + r * 64 + u * 4);
                }
            }
        }
        asm volatile("s_waitcnt lgkmcnt(0)" ::: "memory");
        __builtin_amdgcn_sched_barrier(0);

        // ---- issue next node's loads: in flight under convert+MFMA+epilogue ----
        if (nn < n_nodes) {
            const float* xb = x + (size_t)nn * NODE_ELTS;
#pragma unroll
            for (int i = 0; i < 8; ++i) gload16(xb + goff[i], my + i * 256);
        }
        __builtin_amdgcn_sched_barrier(0);

        // ---- convert to bf16 A-fragments ----
        bf16x8 Af[2][2];
#pragma unroll
        for (int m = 0; m < 2; ++m) {
#pragma unroll
            for (int s = 0; s < 2; ++s) {
#pragma unroll
                for (int jj = 0; jj < 4; ++jj) {
                    Af[m][s][jj]     = f2bf(q[m][s][0][jj]);
                    Af[m][s][4 + jj] = f2bf(q[m][s][1][jj]);
                }
            }
        }

        // ---- 16 MFMAs ----
        f32x4 acc[2][4];
#pragma unroll
        for (int m = 0; m < 2; ++m)
#pragma unroll
            for (int t = 0; t < 4; ++t)
                acc[m][t] = (f32x4){0.f, 0.f, 0.f, 0.f};

#pragma unroll
        for (int m = 0; m < 2; ++m) {
#pragma unroll
            for (int t = 0; t < 4; ++t) {
                acc[m][t] = __builtin_amdgcn_mfma_f32_16x16x32_bf16(
                    Af[m][0], Wf[t][0], acc[m][t], 0, 0, 0);
                acc[m][t] = __builtin_amdgcn_mfma_f32_16x16x32_bf16(
                    Af[m][1], Wf[t][1], acc[m][t], 0, 0, 0);
            }
        }

        // ---- epilogue: max over 32 rows per column, relu(max + bias) ----
        float res[4];
#pragma unroll
        for (int t = 0; t < 4; ++t) {
            float v0 = fmaxf(acc[0][t][0], acc[1][t][0]);
            float v1 = fmaxf(acc[0][t][1], acc[1][t][1]);
            float v2 = fmaxf(acc[0][t][2], acc[1][t][2]);
            float v3 = fmaxf(acc[0][t][3], acc[1][t][3]);
            float r = fmaxf(fmaxf(v0, v1), fmaxf(v2, v3));
            r = fmaxf(r, __shfl_xor(r, 16));
            r = fmaxf(r, __shfl_xor(r, 32));
            res[t] = fmaxf(r + bias[t], 0.0f);
        }

        float val = (lg == 0) ? res[0] : (lg == 1) ? res[1] : (lg == 2) ? res[2] : res[3];
        out[(size_t)n * NOUT + lane] = val;
    }
}

extern "C" void kernel_launch(void* const* d_in, const int* in_sizes, int n_in,
                              void* d_out, int out_size, void* d_ws, size_t ws_size,
                              hipStream_t stream) {
    const float* x = (const float*)d_in[0];
    const float* W = (const float*)d_in[1];
    const float* b = (const float*)d_in[2];
    float* out = (float*)d_out;

    const int n_nodes = in_sizes[0] / (KNEIGH * NIN);  // 100000
    // 1000 blocks x 4 waves = 4000 waves x exactly 25 nodes (no tail);
    // 32KB LDS/block -> 4-5 blocks/CU resident.
    const int blocks = 1000;
    const int wave_stride = blocks * 4;

    hipLaunchKernelGGL(edge_mfma_kernel, dim3(blocks), dim3(256), 0, stream,
                       x, W, b, out, n_nodes, wave_stride);
}